// Round 3
// baseline (106.586 us; speedup 1.0000x reference)
//
#include <hip/hip_runtime.h>
#include <math.h>

#define N_INST 64
#define HW 64000        // 200*320 pixels
#define TP 64           // pixels per k_mask block
#define MASK_BLOCKS (HW / TP)   // 1000

__device__ __forceinline__ float sigmoidf_(float x) {
    return 1.0f / (1.0f + __expf(-x));
}

// -------- workspace layout (floats) --------
// [0,     4096)   OT[j][i]  (O transposed)
// [4096,  20480)  AfpT[c][i] = relu(U[c][cls_i-1]) * P[c]   (256 x 64)
// [20480, 36864)  BfT[c][i]  = relu(V[c][cls_i-1])          (256 x 64)

// K0: gather per-instance class columns into dense transposed layouts.
// grid 64 x 256. Block b handles c-rows 4b..4b+3; lane = instance i.
// Both tables are the same pattern: per-lane gather (stride 320 B), coalesced write.
__global__ void k_gather(const int* __restrict__ cls,
                         const float* __restrict__ U_w,
                         const float* __restrict__ V_w,
                         const float* __restrict__ P_w,
                         float* __restrict__ AfpT,
                         float* __restrict__ BfT) {
    const int tid = threadIdx.x;                 // 0..255
    const int c = blockIdx.x * 4 + (tid >> 6);   // 0..255
    const int i = tid & 63;
    const int ci = cls[i] - 1;                   // 0..79
    float u = U_w[c * 80 + ci];
    float v = V_w[c * 80 + ci];
    AfpT[c * 64 + i] = fmaxf(u, 0.0f) * P_w[c];
    BfT[c * 64 + i]  = fmaxf(v, 0.0f);
}

// K1: fused pair-logit + relu(R - R^T). Block = one i, lane = j.
// Computes BOTH L[i][j] and L[j][i] in-lane:
//   Lij = sum_c AfpT[c][i] (s_load) * BfT[c][j]  (coalesced)
//   Lji = sum_c AfpT[c][j] (coalesced) * BfT[c][i] (s_load)
// then O[i][j] = relu(sig(Lij) - sig(Lji)) directly -- no logit round-trip,
// no separate k_relu_R launch.
__global__ __launch_bounds__(64) void k_pairO(const float* __restrict__ bbox,
                                              const float* __restrict__ AfpT,
                                              const float* __restrict__ BfT,
                                              const float* __restrict__ Wc_w,
                                              const float* __restrict__ P_w,
                                              float* __restrict__ O_out,
                                              float* __restrict__ OT_ws) {
    const int i = blockIdx.x;
    const int j = threadIdx.x;

    float accA = 0.0f;   // L[i][j]
    float accB = 0.0f;   // L[j][i]
#pragma unroll 16
    for (int c = 0; c < 256; ++c) {
        float ai = AfpT[c * 64 + i];   // wave-uniform -> s_load
        float bi = BfT[c * 64 + i];    // wave-uniform -> s_load
        float aj = AfpT[c * 64 + j];   // coalesced
        float bj = BfT[c * 64 + j];    // coalesced
        accA = fmaf(ai, bj, accA);
        accB = fmaf(aj, bi, accB);
    }

    // bbox geometry, both directions (i-side wave-uniform, j-side per-lane)
    float xmin_i = bbox[i * 5 + 1], ymin_i = bbox[i * 5 + 2];
    float xmax_i = bbox[i * 5 + 3], ymax_i = bbox[i * 5 + 4];
    float xmin_j = bbox[j * 5 + 1], ymin_j = bbox[j * 5 + 2];
    float xmax_j = bbox[j * 5 + 3], ymax_j = bbox[j * 5 + 4];
    float wi = xmax_i - xmin_i + 1.0f, hi = ymax_i - ymin_i + 1.0f;
    float wj = xmax_j - xmin_j + 1.0f, hj = ymax_j - ymin_j + 1.0f;
    float xci = xmin_i + 0.5f * wi, yci = ymin_i + 0.5f * hi;
    float xcj = xmin_j + 0.5f * wj, ycj = ymin_j + 0.5f * hj;

    float dx_ij = -(xci - xcj) / wi;
    float dy_ij = -(yci - ycj) / hi;
    float dw_ij = __logf(wj / wi);
    float dh_ij = __logf(hj / hi);
    float dx_ji = -(xcj - xci) / wj;
    float dy_ji = -(ycj - yci) / hj;
    float dw_ji = -dw_ij;
    float dh_ji = -dh_ij;

#pragma unroll 8
    for (int o = 0; o < 128; ++o) {
        float w0 = Wc_w[o * 4 + 0], w1 = Wc_w[o * 4 + 1];
        float w2 = Wc_w[o * 4 + 2], w3 = Wc_w[o * 4 + 3];
        float p  = P_w[256 + o];
        float sA = dx_ij * w0 + dy_ij * w1 + dw_ij * w2 + dh_ij * w3;
        float sB = dx_ji * w0 + dy_ji * w1 + dw_ji * w2 + dh_ji * w3;
        accA = fmaf(fmaxf(sA, 0.0f), p, accA);
        accB = fmaf(fmaxf(sB, 0.0f), p, accB);
    }

    float r = sigmoidf_(accA) - sigmoidf_(accB);
    r = fmaxf(r, 0.0f);                // diagonal: accA==accB -> exactly 0
    O_out[i * 64 + j] = r;             // coalesced
    OT_ws[j * 64 + i] = r;             // scattered, 4096 elements total
}

// K2: fused mask update (unchanged from R2 -- isolates this round's change).
// Block = 64-pixel tile x all 64 instances; t=sigmoid(mask) computed once into
// LDS; each thread owns a 4i x 4p micro-tile: per j, 2x ds_read_b128 + 16 FMA.
__global__ __launch_bounds__(256) void k_mask(const float* __restrict__ mask,
                                              const float* __restrict__ OT,
                                              float* __restrict__ out) {
    __shared__ float t_lds[64][64];   // t[j][p_local]
    __shared__ float o_lds[64][64];   // O^T[j][i]
    const int tid = threadIdx.x;
    const int pbase = blockIdx.x * TP;

    // stage O^T (coalesced: 16 floats/thread)
#pragma unroll
    for (int k = 0; k < 16; ++k) {
        int idx = k * 256 + tid;
        ((float*)o_lds)[idx] = OT[idx];
    }
    // phase 1: sigmoid into LDS (coalesced mask reads)
    {
        const int j0 = tid >> 6;   // 0..3
        const int p  = tid & 63;
#pragma unroll
        for (int k = 0; k < 16; ++k) {
            int j = j0 * 16 + k;
            float m = mask[j * HW + pbase + p];
            t_lds[j][p] = sigmoidf_(m);
        }
    }
    __syncthreads();

    // phase 2
    const int pg = tid & 15;   // pixels pg*4 .. pg*4+3
    const int ig = tid >> 4;   // i = ig*4 .. ig*4+3
    float acc[4][4];
#pragma unroll
    for (int a = 0; a < 4; ++a)
#pragma unroll
        for (int b = 0; b < 4; ++b) acc[a][b] = 0.0f;

#pragma unroll 8
    for (int j = 0; j < 64; ++j) {
        float4 t4 = *(const float4*)&t_lds[j][pg * 4];
        float4 o4 = *(const float4*)&o_lds[j][ig * 4];
        acc[0][0] = fmaf(o4.x, t4.x, acc[0][0]);
        acc[0][1] = fmaf(o4.x, t4.y, acc[0][1]);
        acc[0][2] = fmaf(o4.x, t4.z, acc[0][2]);
        acc[0][3] = fmaf(o4.x, t4.w, acc[0][3]);
        acc[1][0] = fmaf(o4.y, t4.x, acc[1][0]);
        acc[1][1] = fmaf(o4.y, t4.y, acc[1][1]);
        acc[1][2] = fmaf(o4.y, t4.z, acc[1][2]);
        acc[1][3] = fmaf(o4.y, t4.w, acc[1][3]);
        acc[2][0] = fmaf(o4.z, t4.x, acc[2][0]);
        acc[2][1] = fmaf(o4.z, t4.y, acc[2][1]);
        acc[2][2] = fmaf(o4.z, t4.z, acc[2][2]);
        acc[2][3] = fmaf(o4.z, t4.w, acc[2][3]);
        acc[3][0] = fmaf(o4.w, t4.x, acc[3][0]);
        acc[3][1] = fmaf(o4.w, t4.y, acc[3][1]);
        acc[3][2] = fmaf(o4.w, t4.z, acc[3][2]);
        acc[3][3] = fmaf(o4.w, t4.w, acc[3][3]);
    }

    // epilogue: out[i][p] = m[i][p] * (1 - t[i][p] * w[i][p])
#pragma unroll
    for (int a = 0; a < 4; ++a) {
        const int i = ig * 4 + a;
        float4 ti = *(const float4*)&t_lds[i][pg * 4];
        float4 mi = *(const float4*)(mask + (size_t)i * HW + pbase + pg * 4);  // L1-hot
        float4 r;
        r.x = mi.x * (1.0f - ti.x * acc[a][0]);
        r.y = mi.y * (1.0f - ti.y * acc[a][1]);
        r.z = mi.z * (1.0f - ti.z * acc[a][2]);
        r.w = mi.w * (1.0f - ti.w * acc[a][3]);
        *(float4*)(out + (size_t)i * HW + pbase + pg * 4) = r;
    }
}

extern "C" void kernel_launch(void* const* d_in, const int* in_sizes, int n_in,
                              void* d_out, int out_size, void* d_ws, size_t ws_size,
                              hipStream_t stream) {
    const float* mask = (const float*)d_in[0];
    const float* bbox = (const float*)d_in[1];
    const int*   cls  = (const int*)d_in[2];
    const float* U_w  = (const float*)d_in[3];
    const float* V_w  = (const float*)d_in[4];
    const float* Wc_w = (const float*)d_in[5];
    const float* P_w  = (const float*)d_in[6];

    float* out_mask = (float*)d_out;                         // 4,096,000 floats
    float* out_O    = (float*)d_out + (size_t)N_INST * HW;   // 4096 floats

    float* ws    = (float*)d_ws;
    float* OT    = ws;           // 4096
    float* AfpT  = ws + 4096;    // 16384
    float* BfT   = ws + 20480;   // 16384

    k_gather<<<64, 256, 0, stream>>>(cls, U_w, V_w, P_w, AfpT, BfT);
    k_pairO<<<64, 64, 0, stream>>>(bbox, AfpT, BfT, Wc_w, P_w, out_O, OT);
    k_mask<<<MASK_BLOCKS, 256, 0, stream>>>(mask, OT, out_mask);
}